// Round 6
// baseline (187.120 us; speedup 1.0000x reference)
//
#include <hip/hip_runtime.h>

#define HW (512 * 512)

typedef float vfloat4 __attribute__((ext_vector_type(4)));  // clang-native: OK for nontemporal builtins

constexpr float BWIDTH = 1.0f / 15.0f;
constexpr float DELTA = 3e-5f;        // guard >= ~2.5x the 1.2e-5 fast-path error bound

// R6: 1-row-per-wave rolling kernel, register-dieted for TLP.
// 8192 waves (1 row each), ONE 32-reg logits buffer reused for rows r-1,r,r+1,
// two-pass epilogue (inv normalizers first, per-class re-gather+store second)
// so no res[4][2][4] liveness. launch_bounds(256,7) -> <=73 VGPR -> 28 waves/CU.
// Neighbor counts via packed-nibble SWAR in registers; no __syncthreads anywhere.
__global__ __launch_bounds__(256, 7) void nectar_binning_kernel(
    const float* __restrict__ logits,      // [16,4,512,512]
    const float* __restrict__ val_freqs,   // [4,9,15]
    float* __restrict__ out)               // [16,4,512,512]
{
    __shared__ float vf[540];

    const int tid  = (int)threadIdx.x;
    const int lane = tid & 63;
    const int wv   = tid >> 6;

    // vf: per-wave redundant preload (identical values from all waves -> benign
    // race; each wave reads only after its own ds_writes, ordered by lgkmcnt).
    // Issued FIRST: in-order vmcnt retirement means the ds_write waits only on
    // these 9 loads, not on the row loads issued after.
    float vfr[9];
    #pragma unroll
    for (int i = 0; i < 9; i++) {
        int idx = 64 * i + lane;
        vfr[i] = (idx < 540) ? val_freqs[idx] : 0.f;
    }

    // segment map: 8192 wave-segments of 1 row; waves of a block take ADJACENT
    // rows (halo rows shared via L1/L2); XCD-chunk block swizzle (bijective,
    // 2048 % 8 == 0) keeps neighboring rows on one XCD L2.
    const unsigned bi  = blockIdx.x;
    const unsigned bsw = ((bi & 7u) << 8) | (bi >> 3);
    const int seg = (int)(4u * bsw) + wv;   // 0..8191 = global wave id
    const int b   = seg >> 9;               // batch (512 rows/image)
    const int row = seg & 511;              // output row

    const float* lb = logits + (size_t)b * 4 * HW;
    float*       ob = out    + (size_t)b * 4 * HW;
    const int colA = 4 * lane;
    const int colB = 256 + 4 * lane;

    // the ONE row buffer (32 VGPR) — reused for all three rows
    vfloat4 x[4][2];
    auto LOADROW = [&](int r) {
        const float* rp = lb + (r << 9);
        #pragma unroll
        for (int c = 0; c < 4; c++) {
            x[c][0] = *reinterpret_cast<const vfloat4*>(rp + (size_t)c * HW + colA);
            x[c][1] = *reinterpret_cast<const vfloat4*>(rp + (size_t)c * HW + colB);
        }
    };

    // argmax -> nib16 only (halo rows). First-index tie-break, verbatim since R2.
    auto NIBROW = [&](unsigned (&N)[2][2]) {
        #pragma unroll
        for (int h = 0; h < 2; h++) {
            unsigned n[4];
            #pragma unroll
            for (int j = 0; j < 4; j++) {
                float x0 = x[0][h][j], x1 = x[1][h][j], x2 = x[2][h][j], x3 = x[3][h][j];
                int c = 0; float best = x0;
                if (x1 > best) { best = x1; c = 1; }
                if (x2 > best) { best = x2; c = 2; }
                if (x3 > best) { best = x3; c = 3; }
                n[j] = 1u << (4 * c);
            }
            N[h][0] = n[0] | (n[1] << 16);
            N[h][1] = n[2] | (n[3] << 16);
        }
    };

    // argmax + softmax->bins (center row). Numeric path verbatim from R0-R5.
    auto NIBPBROW = [&](unsigned (&N)[2][2], unsigned (&P)[2][2]) {
        #pragma unroll
        for (int h = 0; h < 2; h++) {
            unsigned n[4], pbv[4];
            #pragma unroll
            for (int j = 0; j < 4; j++) {
                float x0 = x[0][h][j], x1 = x[1][h][j], x2 = x[2][h][j], x3 = x[3][h][j];
                int c = 0; float best = x0;
                if (x1 > best) { best = x1; c = 1; }
                if (x2 > best) { best = x2; c = 2; }
                if (x3 > best) { best = x3; c = 3; }
                n[j] = 1u << (4 * c);

                float m = fmaxf(fmaxf(x0, x1), fmaxf(x2, x3));
                float t0 = x0 - m, t1 = x1 - m, t2 = x2 - m, t3 = x3 - m;
                // fast path: native exp + rcp; |q_fast - q_exact| <= ~1.2e-5 << DELTA
                float f0 = __expf(t0), f1 = __expf(t1), f2 = __expf(t2), f3 = __expf(t3);
                float sf = ((f0 + f1) + f2) + f3;
                float rs = __builtin_amdgcn_rcpf(sf);
                float q[4];
                q[0] = (f0 * rs) * 15.0f; q[1] = (f1 * rs) * 15.0f;
                q[2] = (f2 * rs) * 15.0f; q[3] = (f3 * rs) * 15.0f;
                bool slow = false;
                #pragma unroll
                for (int c2 = 0; c2 < 4; c2++) {
                    float fr = q[c2] - floorf(q[c2]);
                    slow |= (fr < DELTA) | (fr > 1.0f - DELTA);
                }
                if (slow) {  // exact ocml-exp + IEEE-divide chain (matches np)
                    float e0 = expf(t0), e1 = expf(t1), e2 = expf(t2), e3 = expf(t3);
                    float s = ((e0 + e1) + e2) + e3;
                    q[0] = (e0 / s) / BWIDTH; q[1] = (e1 / s) / BWIDTH;
                    q[2] = (e2 / s) / BWIDTH; q[3] = (e3 / s) / BWIDTH;
                }
                unsigned pb = 0;
                #pragma unroll
                for (int c2 = 0; c2 < 4; c2++) {
                    int bin = (int)q[c2];
                    bin = bin > 14 ? 14 : bin;
                    pb |= (unsigned)bin << (4 * c2);
                }
                pbv[j] = pb;
            }
            N[h][0] = n[0]   | (n[1]   << 16);
            N[h][1] = n[2]   | (n[3]   << 16);
            P[h][0] = pbv[0] | (pbv[1] << 16);
            P[h][1] = pbv[2] | (pbv[3] << 16);
        }
    };

    unsigned T[2][2], M[2][2], B[2][2], PC[2][2];

    // ---- rolling chain: r-1 -> T, r -> M/PC, r+1 -> B, all through one buffer ----
    LOADROW(row > 0 ? row - 1 : 0);
    #pragma unroll
    for (int i = 0; i < 9; i++) {            // vf write: waits only the vfr loads
        int idx = 64 * i + lane;
        if (idx < 540) vf[idx] = vfr[i];
    }
    NIBROW(T);
    if (row == 0) { T[0][0] = T[0][1] = T[1][0] = T[1][1] = 0; }

    LOADROW(row);
    NIBPBROW(M, PC);

    LOADROW(row < 511 ? row + 1 : 511);
    NIBROW(B);
    if (row == 511) { B[0][0] = B[0][1] = B[1][0] = B[1][1] = 0; }

    // ---- epilogue: SWAR neighbor counts + two-pass gather/normalize + NT store ----
    unsigned C[2][2];
    #pragma unroll
    for (int h = 0; h < 2; h++) {
        C[h][0] = T[h][0] + M[h][0] + B[h][0];
        C[h][1] = T[h][1] + M[h][1] + B[h][1];
    }
    // cross-lane / cross-half colsum edges (cols 4L-1 and 4L+4 per half), verbatim
    unsigned upA = __shfl_up(C[0][1], 1) >> 16;   if (lane == 0)  upA = 0;          // col -1: image edge
    unsigned ebA = __shfl(C[0][1], 63) >> 16;                                        // col 255 -> halfB lane0
    unsigned upB = __shfl_up(C[1][1], 1) >> 16;   if (lane == 0)  upB = ebA;
    unsigned e0B = __shfl(C[1][0], 0) & 0xFFFFu;                                     // col 256 -> halfA lane63
    unsigned dnA = __shfl_down(C[0][0], 1) & 0xFFFFu; if (lane == 63) dnA = e0B;
    unsigned dnB = __shfl_down(C[1][0], 1) & 0xFFFFu; if (lane == 63) dnB = 0;       // col 512: image edge
    const unsigned up[2] = {upA, upB}, dn[2] = {dnA, dnB};

    unsigned PKw[2][2];
    #pragma unroll
    for (int h = 0; h < 2; h++) {
        // L(j)=C(j-1), R(j)=C(j+1) packed; note L-word1 == R-word0 (= c1|c2<<16)
        unsigned L0 = (C[h][0] << 16) | up[h];
        unsigned R0 = (C[h][0] >> 16) | (C[h][1] << 16);
        unsigned R1 = (C[h][1] >> 16) | (dn[h] << 16);
        PKw[h][0] = C[h][0] + L0 + R0 - M[h][0];   // nibble-wise 3x3 sum minus center, <= 8
        PKw[h][1] = C[h][1] + R0 + R1 - M[h][1];
    }

    // pass 1: per-px normalizer only (no 32-reg res matrix live)
    float inv[2][4];
    #pragma unroll
    for (int h = 0; h < 2; h++) {
        #pragma unroll
        for (int j = 0; j < 4; j++) {
            unsigned pk = (PKw[h][j >> 1] >> (16 * (j & 1))) & 0xFFFFu;
            unsigned pb = (PC[h][j >> 1] >> (16 * (j & 1))) & 0xFFFFu;
            float cs = 0.0f;
            #pragma unroll
            for (int c = 0; c < 4; c++) {
                int cnt = (int)((pk >> (4 * c)) & 0xFu);   // [0,8]
                int bin = (int)((pb >> (4 * c)) & 0xFu);   // [0,14]
                cs += vf[c * 135 + cnt * 15 + bin];        // ref class order
            }
            if (cs == 0.0f) cs = 1.0f;
            inv[h][j] = __builtin_amdgcn_rcpf(cs);         // tolerance 1.97e-2 >> 1 ULP
        }
    }

    // pass 2: per-class re-gather (identical LDS reads -> bit-identical product) + store
    float* rp = ob + (row << 9);
    #pragma unroll
    for (int c = 0; c < 4; c++) {
        vfloat4 v0, v1;
        #pragma unroll
        for (int j = 0; j < 4; j++) {
            unsigned pk0 = (PKw[0][j >> 1] >> (16 * (j & 1))) & 0xFFFFu;
            unsigned pb0 = (PC[0][j >> 1] >> (16 * (j & 1))) & 0xFFFFu;
            v0[j] = vf[c * 135 + (int)((pk0 >> (4 * c)) & 0xFu) * 15
                               + (int)((pb0 >> (4 * c)) & 0xFu)] * inv[0][j];
            unsigned pk1 = (PKw[1][j >> 1] >> (16 * (j & 1))) & 0xFFFFu;
            unsigned pb1 = (PC[1][j >> 1] >> (16 * (j & 1))) & 0xFFFFu;
            v1[j] = vf[c * 135 + (int)((pk1 >> (4 * c)) & 0xFu) * 15
                               + (int)((pb1 >> (4 * c)) & 0xFu)] * inv[1][j];
        }
        __builtin_nontemporal_store(v0, reinterpret_cast<vfloat4*>(rp + (size_t)c * HW + colA));
        __builtin_nontemporal_store(v1, reinterpret_cast<vfloat4*>(rp + (size_t)c * HW + colB));
    }
}

extern "C" void kernel_launch(void* const* d_in, const int* in_sizes, int n_in,
                              void* d_out, int out_size, void* d_ws, size_t ws_size,
                              hipStream_t stream) {
    const float* logits    = (const float*)d_in[0];
    const float* val_freqs = (const float*)d_in[1];
    float* out             = (float*)d_out;

    dim3 block(256, 1, 1);
    dim3 grid(2048, 1, 1);   // 8192 wave-segments / 4 waves per block
    hipLaunchKernelGGL(nectar_binning_kernel, grid, block, 0, stream,
                       logits, val_freqs, out);
}

// Round 7
// 117.412 us; speedup vs baseline: 1.5937x; 1.5937x over previous
//
#include <hip/hip_runtime.h>

#define HW (512 * 512)

typedef float vfloat4 __attribute__((ext_vector_type(4)));
typedef unsigned int vuint4 __attribute__((ext_vector_type(4)));

constexpr float BWIDTH = 1.0f / 15.0f;
constexpr float DELTA = 3e-5f;        // guard >= ~2.5x the 1.2e-5 fast-path error bound

// ============================================================================
// Two-kernel split: K1 = pure read-stream (logits -> compact u32/px),
// K2 = pure write-stream (compact -> calibrated output). The compact map
// (16.8 MB) lives in d_ws and is L3-resident between kernels.
// compact word: bits 0..15 = 4x4-bit conf bins, bits 16..17 = argmax class.
// ============================================================================

__global__ __launch_bounds__(256) void nectar_k1_pack(
    const float* __restrict__ logits,      // [16,4,512,512]
    unsigned* __restrict__ cmp)            // [16,512,512] compact
{
    const int gid = (int)(blockIdx.x * 256 + threadIdx.x);   // 0..1048575
    const int b   = gid >> 16;             // 65536 strips per image
    const int off = (gid & 65535) << 2;    // px offset within image

    const float* lb = logits + (size_t)b * 4 * HW + off;
    vfloat4 x0 = *reinterpret_cast<const vfloat4*>(lb);
    vfloat4 x1 = *reinterpret_cast<const vfloat4*>(lb + HW);
    vfloat4 x2 = *reinterpret_cast<const vfloat4*>(lb + 2 * HW);
    vfloat4 x3 = *reinterpret_cast<const vfloat4*>(lb + 3 * HW);

    vuint4 o;
    #pragma unroll
    for (int j = 0; j < 4; j++) {
        float a0 = x0[j], a1 = x1[j], a2 = x2[j], a3 = x3[j];
        // argmax(logits) == argmax(softmax), first-index tie-break (verbatim since R2)
        int c = 0; float best = a0;
        if (a1 > best) { best = a1; c = 1; }
        if (a2 > best) { best = a2; c = 2; }
        if (a3 > best) { best = a3; c = 3; }

        float m = fmaxf(fmaxf(a0, a1), fmaxf(a2, a3));
        float t0 = a0 - m, t1 = a1 - m, t2 = a2 - m, t3 = a3 - m;
        // fast path: native exp + rcp; |q_fast - q_exact| <= ~1.2e-5 << DELTA
        float f0 = __expf(t0), f1 = __expf(t1), f2 = __expf(t2), f3 = __expf(t3);
        float sf = ((f0 + f1) + f2) + f3;
        float rs = __builtin_amdgcn_rcpf(sf);
        float q[4];
        q[0] = (f0 * rs) * 15.0f; q[1] = (f1 * rs) * 15.0f;
        q[2] = (f2 * rs) * 15.0f; q[3] = (f3 * rs) * 15.0f;
        bool slow = false;
        #pragma unroll
        for (int c2 = 0; c2 < 4; c2++) {
            float fr = q[c2] - floorf(q[c2]);
            slow |= (fr < DELTA) | (fr > 1.0f - DELTA);
        }
        if (slow) {  // exact ocml-exp + IEEE-divide chain (matches np; verbatim)
            float e0 = expf(t0), e1 = expf(t1), e2 = expf(t2), e3 = expf(t3);
            float s = ((e0 + e1) + e2) + e3;
            q[0] = (e0 / s) / BWIDTH; q[1] = (e1 / s) / BWIDTH;
            q[2] = (e2 / s) / BWIDTH; q[3] = (e3 / s) / BWIDTH;
        }
        unsigned pb = 0;
        #pragma unroll
        for (int c2 = 0; c2 < 4; c2++) {
            int bin = (int)q[c2];
            bin = bin > 14 ? 14 : bin;
            pb |= (unsigned)bin << (4 * c2);
        }
        o[j] = pb | ((unsigned)c << 16);
    }
    // regular (cached) store: re-read by K2 through L2/L3
    *reinterpret_cast<vuint4*>(cmp + (size_t)b * HW + off) = o;
}

__global__ __launch_bounds__(256) void nectar_k2_gather(
    const unsigned* __restrict__ cmp,      // [16,512,512] compact
    const float* __restrict__ val_freqs,   // [4,9,15]
    float* __restrict__ out)               // [16,4,512,512]
{
    __shared__ float vf[540];

    const int tid  = (int)threadIdx.x;
    const int lane = tid & 63;
    const int wv   = tid >> 6;

    // vf: per-wave redundant preload (benign race, lgkm-ordered per wave; verbatim R4-R6)
    float vfr[9];
    #pragma unroll
    for (int i = 0; i < 9; i++) {
        int idx = 64 * i + lane;
        vfr[i] = (idx < 540) ? val_freqs[idx] : 0.f;
    }

    // 8192 wave-rows; XCD-chunk block swizzle (bijective, 2048 % 8 == 0)
    const unsigned bi  = blockIdx.x;
    const unsigned bsw = ((bi & 7u) << 8) | (bi >> 3);
    const int seg = (int)(4u * bsw) + wv;   // 0..8191
    const int b   = seg >> 9;
    const int row = seg & 511;

    const unsigned* cb = cmp + (size_t)b * HW;
    float*          ob = out + (size_t)b * 4 * HW;
    const int colA = 4 * lane;
    const int colB = 256 + 4 * lane;

    vuint4 tA, tB, mA, mB, bA, bB;
    {
        const unsigned* rp = cb + ((row > 0 ? row - 1 : 0) << 9);
        tA = *reinterpret_cast<const vuint4*>(rp + colA);
        tB = *reinterpret_cast<const vuint4*>(rp + colB);
        rp = cb + (row << 9);
        mA = *reinterpret_cast<const vuint4*>(rp + colA);
        mB = *reinterpret_cast<const vuint4*>(rp + colB);
        rp = cb + ((row < 511 ? row + 1 : 511) << 9);
        bA = *reinterpret_cast<const vuint4*>(rp + colA);
        bB = *reinterpret_cast<const vuint4*>(rp + colB);
    }
    #pragma unroll
    for (int i = 0; i < 9; i++) {           // vf write: waits only the vfr loads
        int idx = 64 * i + lane;
        if (idx < 540) vf[idx] = vfr[i];
    }

    // nib16 packing: 2 px/word, nib = 1<<(4*class)
    auto NIBW = [](unsigned w0, unsigned w1) -> unsigned {
        return (1u << (4 * ((w0 >> 16) & 3u))) | ((1u << (4 * ((w1 >> 16) & 3u))) << 16);
    };
    unsigned T[2][2] = {{NIBW(tA.x, tA.y), NIBW(tA.z, tA.w)},
                        {NIBW(tB.x, tB.y), NIBW(tB.z, tB.w)}};
    unsigned M[2][2] = {{NIBW(mA.x, mA.y), NIBW(mA.z, mA.w)},
                        {NIBW(mB.x, mB.y), NIBW(mB.z, mB.w)}};
    unsigned B[2][2] = {{NIBW(bA.x, bA.y), NIBW(bA.z, bA.w)},
                        {NIBW(bB.x, bB.y), NIBW(bB.z, bB.w)}};
    if (row == 0)   { T[0][0] = T[0][1] = T[1][0] = T[1][1] = 0; }
    if (row == 511) { B[0][0] = B[0][1] = B[1][0] = B[1][1] = 0; }
    const unsigned P[2][2] = {
        {(mA.x & 0xFFFFu) | ((mA.y & 0xFFFFu) << 16), (mA.z & 0xFFFFu) | ((mA.w & 0xFFFFu) << 16)},
        {(mB.x & 0xFFFFu) | ((mB.y & 0xFFFFu) << 16), (mB.z & 0xFFFFu) | ((mB.w & 0xFFFFu) << 16)}};

    // SWAR neighbor counts (verbatim R5): colsum T+M+B, 3x3 sum minus center
    unsigned C[2][2];
    #pragma unroll
    for (int h = 0; h < 2; h++) {
        C[h][0] = T[h][0] + M[h][0] + B[h][0];
        C[h][1] = T[h][1] + M[h][1] + B[h][1];
    }
    unsigned upA = __shfl_up(C[0][1], 1) >> 16;   if (lane == 0)  upA = 0;
    unsigned ebA = __shfl(C[0][1], 63) >> 16;
    unsigned upB = __shfl_up(C[1][1], 1) >> 16;   if (lane == 0)  upB = ebA;
    unsigned e0B = __shfl(C[1][0], 0) & 0xFFFFu;
    unsigned dnA = __shfl_down(C[0][0], 1) & 0xFFFFu; if (lane == 63) dnA = e0B;
    unsigned dnB = __shfl_down(C[1][0], 1) & 0xFFFFu; if (lane == 63) dnB = 0;
    const unsigned up[2] = {upA, upB}, dn[2] = {dnA, dnB};

    float res[4][2][4];
    #pragma unroll
    for (int h = 0; h < 2; h++) {
        unsigned L0 = (C[h][0] << 16) | up[h];
        unsigned R0 = (C[h][0] >> 16) | (C[h][1] << 16);
        unsigned R1 = (C[h][1] >> 16) | (dn[h] << 16);
        unsigned PKw[2];
        PKw[0] = C[h][0] + L0 + R0 - M[h][0];
        PKw[1] = C[h][1] + R0 + R1 - M[h][1];
        #pragma unroll
        for (int j = 0; j < 4; j++) {
            unsigned pk = (PKw[j >> 1]  >> (16 * (j & 1))) & 0xFFFFu;
            unsigned pb = (P[h][j >> 1] >> (16 * (j & 1))) & 0xFFFFu;
            float cs = 0.0f;
            float cal[4];
            #pragma unroll
            for (int c = 0; c < 4; c++) {
                int cnt = (int)((pk >> (4 * c)) & 0xFu);   // [0,8]
                int bin = (int)((pb >> (4 * c)) & 0xFu);   // [0,14]
                float v = vf[c * 135 + cnt * 15 + bin];
                cal[c] = v;
                cs += v;                                   // ref class order
            }
            if (cs == 0.0f) cs = 1.0f;
            float inv = __builtin_amdgcn_rcpf(cs);         // tolerance 1.97e-2 >> 1 ULP
            #pragma unroll
            for (int c = 0; c < 4; c++) res[c][h][j] = cal[c] * inv;
        }
    }
    float* rp = ob + (row << 9);
    #pragma unroll
    for (int c = 0; c < 4; c++) {
        vfloat4 v0; v0.x = res[c][0][0]; v0.y = res[c][0][1]; v0.z = res[c][0][2]; v0.w = res[c][0][3];
        vfloat4 v1; v1.x = res[c][1][0]; v1.y = res[c][1][1]; v1.z = res[c][1][2]; v1.w = res[c][1][3];
        __builtin_nontemporal_store(v0, reinterpret_cast<vfloat4*>(rp + (size_t)c * HW + colA));
        __builtin_nontemporal_store(v1, reinterpret_cast<vfloat4*>(rp + (size_t)c * HW + colB));
    }
}

// ============================================================================
// Fallback: R2 fused full-width row-panel kernel (measured best fused, absmax 0).
// Used only if ws_size < 16.8 MB.
// ============================================================================
constexpr int CWP = 516;

__global__ __launch_bounds__(512) void nectar_binning_fused(
    const float* __restrict__ logits,
    const float* __restrict__ val_freqs,
    float* __restrict__ out)
{
    __shared__ unsigned int cls[6 * CWP];
    __shared__ float vf[540];

    const unsigned int f = blockIdx.x;
    const unsigned int l = ((f & 7u) << 8) | (f >> 3);
    const int panel = (int)(l & 127u);
    const int b     = (int)(l >> 7);
    const int h0  = panel * 4;
    const int tid = (int)threadIdx.x;

    for (int i = tid; i < 540; i += 512) vf[i] = val_freqs[i];
    if (tid < 6) { cls[tid * CWP] = 0u; cls[tid * CWP + 513] = 0u; }

    const float* lb = logits + (size_t)b * 4 * HW;

    const int r = tid >> 7;
    const int t = tid & 127;
    const int w = 4 * t;
    const int base = ((h0 + r) << 9) + w;

    vfloat4 xa[4];
    #pragma unroll
    for (int c = 0; c < 4; c++)
        xa[c] = *reinterpret_cast<const vfloat4*>(lb + (size_t)c * HW + base);

    const int hrow = tid >> 8;
    const int p = tid & 255;
    const int hh = hrow ? (h0 + 4) : (h0 - 1);
    const bool hv = (unsigned)hh < 512u;
    float hx[4][2];
    #pragma unroll
    for (int c = 0; c < 4; c++) { hx[c][0] = 0.f; hx[c][1] = 0.f; }
    if (hv) {
        const int hb = (hh << 9) + 2 * p;
        #pragma unroll
        for (int c = 0; c < 4; c++) {
            hx[c][0] = lb[(size_t)c * HW + hb];
            hx[c][1] = lb[(size_t)c * HW + hb + 1];
        }
    }

    auto px_phase1 = [&](float x0, float x1, float x2, float x3,
                         int clsaddr) -> unsigned int {
        int c = 0; float best = x0;
        if (x1 > best) { best = x1; c = 1; }
        if (x2 > best) { best = x2; c = 2; }
        if (x3 > best) { best = x3; c = 3; }
        cls[clsaddr] = 1u << (4 * c);

        float m = fmaxf(fmaxf(x0, x1), fmaxf(x2, x3));
        float t0 = x0 - m, t1 = x1 - m, t2 = x2 - m, t3 = x3 - m;
        float f0 = __expf(t0), f1 = __expf(t1), f2 = __expf(t2), f3 = __expf(t3);
        float sf = ((f0 + f1) + f2) + f3;
        float rs = __builtin_amdgcn_rcpf(sf);
        float q[4];
        q[0] = (f0 * rs) * 15.0f; q[1] = (f1 * rs) * 15.0f;
        q[2] = (f2 * rs) * 15.0f; q[3] = (f3 * rs) * 15.0f;
        bool slow = false;
        #pragma unroll
        for (int c2 = 0; c2 < 4; c2++) {
            float fr = q[c2] - floorf(q[c2]);
            slow |= (fr < DELTA) | (fr > 1.0f - DELTA);
        }
        if (slow) {
            float e0 = expf(t0), e1 = expf(t1), e2 = expf(t2), e3 = expf(t3);
            float s = ((e0 + e1) + e2) + e3;
            q[0] = (e0 / s) / BWIDTH; q[1] = (e1 / s) / BWIDTH;
            q[2] = (e2 / s) / BWIDTH; q[3] = (e3 / s) / BWIDTH;
        }
        unsigned int pb = 0;
        #pragma unroll
        for (int c2 = 0; c2 < 4; c2++) {
            int bin = (int)q[c2];
            bin = bin > 14 ? 14 : bin;
            pb |= (unsigned int)bin << (4 * c2);
        }
        return pb;
    };

    unsigned int pbin[4];
    #pragma unroll
    for (int j = 0; j < 4; j++)
        pbin[j] = px_phase1(xa[0][j], xa[1][j], xa[2][j], xa[3][j],
                            (r + 1) * CWP + 1 + w + j);

    {
        unsigned int v0 = 0, v1 = 0;
        if (hv) {
            int c = 0; float best = hx[0][0];
            if (hx[1][0] > best) { best = hx[1][0]; c = 1; }
            if (hx[2][0] > best) { best = hx[2][0]; c = 2; }
            if (hx[3][0] > best) { best = hx[3][0]; c = 3; }
            v0 = 1u << (4 * c);
            c = 0; best = hx[0][1];
            if (hx[1][1] > best) { best = hx[1][1]; c = 1; }
            if (hx[2][1] > best) { best = hx[2][1]; c = 2; }
            if (hx[3][1] > best) { best = hx[3][1]; c = 3; }
            v1 = 1u << (4 * c);
        }
        const int hl = hrow * 5 * CWP + 1 + 2 * p;
        cls[hl]     = v0;
        cls[hl + 1] = v1;
    }
    __syncthreads();

    const unsigned int* p0 = &cls[r * CWP + w];
    vuint4 ra[3], rb[3];
    #pragma unroll
    for (int k = 0; k < 3; k++) {
        ra[k] = *reinterpret_cast<const vuint4*>(p0 + k * CWP);
        rb[k] = *reinterpret_cast<const vuint4*>(p0 + k * CWP + 4);
    }
    unsigned int colsum[6], mid[6];
    #pragma unroll
    for (int k = 0; k < 6; k++) {
        unsigned int a0 = (k < 4) ? ra[0][k] : rb[0][k - 4];
        unsigned int a1 = (k < 4) ? ra[1][k] : rb[1][k - 4];
        unsigned int a2 = (k < 4) ? ra[2][k] : rb[2][k - 4];
        mid[k] = a1;
        colsum[k] = a0 + a1 + a2;
    }

    float res[4][4];
    #pragma unroll
    for (int j = 0; j < 4; j++) {
        unsigned int pk = colsum[j] + colsum[j + 1] + colsum[j + 2] - mid[j + 1];
        unsigned int pb = pbin[j];
        float cs = 0.0f;
        float cal[4];
        #pragma unroll
        for (int c = 0; c < 4; c++) {
            int cnt = (int)((pk >> (4 * c)) & 0xFu);
            int bin = (int)((pb >> (4 * c)) & 0xFu);
            float v = vf[c * 135 + cnt * 15 + bin];
            cal[c] = v;
            cs += v;
        }
        if (cs == 0.0f) cs = 1.0f;
        float inv = __builtin_amdgcn_rcpf(cs);
        #pragma unroll
        for (int c = 0; c < 4; c++) res[c][j] = cal[c] * inv;
    }

    float* ob = out + (size_t)b * 4 * HW + base;
    #pragma unroll
    for (int c = 0; c < 4; c++) {
        vfloat4 v;
        v.x = res[c][0]; v.y = res[c][1]; v.z = res[c][2]; v.w = res[c][3];
        __builtin_nontemporal_store(v, reinterpret_cast<vfloat4*>(ob + (size_t)c * HW));
    }
}

extern "C" void kernel_launch(void* const* d_in, const int* in_sizes, int n_in,
                              void* d_out, int out_size, void* d_ws, size_t ws_size,
                              hipStream_t stream) {
    const float* logits    = (const float*)d_in[0];
    const float* val_freqs = (const float*)d_in[1];
    float* out             = (float*)d_out;

    const size_t needed = (size_t)16 * HW * sizeof(unsigned);   // 16.8 MB compact map
    if (d_ws != nullptr && ws_size >= needed) {
        unsigned* cmp = (unsigned*)d_ws;
        hipLaunchKernelGGL(nectar_k1_pack, dim3(4096), dim3(256), 0, stream,
                           logits, cmp);
        hipLaunchKernelGGL(nectar_k2_gather, dim3(2048), dim3(256), 0, stream,
                           cmp, val_freqs, out);
    } else {
        hipLaunchKernelGGL(nectar_binning_fused, dim3(2048), dim3(512), 0, stream,
                           logits, val_freqs, out);
    }
}